// Round 1
// 1317.608 us; speedup vs baseline: 1.3329x; 1.3329x over previous
//
#include <hip/hip_runtime.h>
#include <cstdint>
#include <cstddef>

#define N_ROWS 2048
#define C_DIM  1024
#define HW     64
#define NH     8
#define HD     128
#define NG     32
#define QKV_DIM 3072

// ---------------------------------------------------------------------------
// Group setup: counts, exclusive offsets, and rows sorted by group.
// ---------------------------------------------------------------------------
__global__ __launch_bounds__(256) void group_setup(const int* __restrict__ bidx,
                                                   int* __restrict__ counts,
                                                   int* __restrict__ offsets,
                                                   int* __restrict__ sorted)
{
    __shared__ int scnt[NG];
    __shared__ int soff[NG];
    __shared__ int sfill[NG];
    int tid = threadIdx.x;
    if (tid < NG) scnt[tid] = 0;
    __syncthreads();
    for (int n = tid; n < N_ROWS; n += 256) atomicAdd(&scnt[bidx[n]], 1);
    __syncthreads();
    if (tid == 0) {
        int run = 0;
        for (int g = 0; g < NG; ++g) { soff[g] = run; run += scnt[g]; }
    }
    __syncthreads();
    if (tid < NG) { counts[tid] = scnt[tid]; offsets[tid] = soff[tid]; sfill[tid] = soff[tid]; }
    __syncthreads();
    for (int n = tid; n < N_ROWS; n += 256) {
        int pos = atomicAdd(&sfill[bidx[n]], 1);
        sorted[pos] = n;
    }
}

// ---------------------------------------------------------------------------
// feat[n][c] = mean over 64 contiguous floats of x.
// ---------------------------------------------------------------------------
__global__ __launch_bounds__(256) void feat_mean(const float* __restrict__ x,
                                                 float* __restrict__ feat)
{
    int tid  = blockIdx.x * 256 + threadIdx.x;
    int gw   = tid >> 6;
    int lane = tid & 63;
    const float4 v = ((const float4*)x)[(size_t)gw * 64 + lane];
    float s = v.x + v.y + v.z + v.w;
    s += __shfl_xor(s, 1);
    s += __shfl_xor(s, 2);
    s += __shfl_xor(s, 4);
    s += __shfl_xor(s, 8);
    if ((lane & 15) == 0) feat[gw * 4 + (lane >> 4)] = s * (1.0f / 64.0f);
}

// ---------------------------------------------------------------------------
// In-place LayerNorm over C=1024.  One block per row.
// ---------------------------------------------------------------------------
__global__ __launch_bounds__(256) void layernorm(float* __restrict__ feat,
                                                 const float* __restrict__ w,
                                                 const float* __restrict__ b)
{
    int n = blockIdx.x, tid = threadIdx.x;
    float* row = feat + (size_t)n * C_DIM;
    float vals[4];
    float s1 = 0.f, s2 = 0.f;
    #pragma unroll
    for (int i = 0; i < 4; ++i) {
        float v = row[tid + i * 256];
        vals[i] = v; s1 += v; s2 += v * v;
    }
    #pragma unroll
    for (int m = 1; m < 64; m <<= 1) { s1 += __shfl_xor(s1, m); s2 += __shfl_xor(s2, m); }
    __shared__ float red[8];
    int wave = tid >> 6, lane = tid & 63;
    if (lane == 0) { red[wave] = s1; red[4 + wave] = s2; }
    __syncthreads();
    s1 = red[0] + red[1] + red[2] + red[3];
    s2 = red[4] + red[5] + red[6] + red[7];
    float mu  = s1 * (1.0f / C_DIM);
    float var = s2 * (1.0f / C_DIM) - mu * mu;
    float rs  = rsqrtf(var + 1e-5f);
    #pragma unroll
    for (int i = 0; i < 4; ++i) {
        int c = tid + i * 256;
        row[c] = (vals[i] - mu) * rs * w[c] + b[c];
    }
}

// ---------------------------------------------------------------------------
// C[M][Nc] = A[M][K] * B[Nc][K]^T + bias
// ---------------------------------------------------------------------------
template<int EPI>
__global__ __launch_bounds__(256) void gemm_bt(
    const float* __restrict__ A, const float* __restrict__ B,
    const float* __restrict__ bias, float* __restrict__ C,
    int M, int Nc, int K,
    const float* __restrict__ gamma,
    const int* __restrict__ counts,
    const int* __restrict__ bidx)
{
    __shared__ float As[16][128];
    __shared__ float Bs[16][128];
    const int tid  = threadIdx.x;
    const int m0   = blockIdx.y * 128, n0 = blockIdx.x * 128;
    const int quad = tid & 3;
    const int lrow = tid >> 2;
    const int tc   = tid & 15;
    const int tr   = tid >> 4;
    float acc[8][8];
    #pragma unroll
    for (int i = 0; i < 8; ++i)
        #pragma unroll
        for (int j = 0; j < 8; ++j) acc[i][j] = 0.f;

    const float* Ap0 = A + (size_t)(m0 + lrow) * K + quad * 4;
    const float* Ap1 = Ap0 + (size_t)64 * K;
    const float* Bp0 = B + (size_t)(n0 + lrow) * K + quad * 4;
    const float* Bp1 = Bp0 + (size_t)64 * K;

    for (int kt = 0; kt < K; kt += 16) {
        float4 a0 = *(const float4*)(Ap0 + kt);
        float4 a1 = *(const float4*)(Ap1 + kt);
        float4 b0 = *(const float4*)(Bp0 + kt);
        float4 b1 = *(const float4*)(Bp1 + kt);
        __syncthreads();
        int kq = quad * 4;
        As[kq+0][lrow] = a0.x; As[kq+1][lrow] = a0.y; As[kq+2][lrow] = a0.z; As[kq+3][lrow] = a0.w;
        As[kq+0][lrow+64] = a1.x; As[kq+1][lrow+64] = a1.y; As[kq+2][lrow+64] = a1.z; As[kq+3][lrow+64] = a1.w;
        Bs[kq+0][lrow] = b0.x; Bs[kq+1][lrow] = b0.y; Bs[kq+2][lrow] = b0.z; Bs[kq+3][lrow] = b0.w;
        Bs[kq+0][lrow+64] = b1.x; Bs[kq+1][lrow+64] = b1.y; Bs[kq+2][lrow+64] = b1.z; Bs[kq+3][lrow+64] = b1.w;
        __syncthreads();
        #pragma unroll
        for (int kk = 0; kk < 16; ++kk) {
            float ar[8], br[8];
            *(float4*)(ar)     = *(const float4*)&As[kk][tr * 8];
            *(float4*)(ar + 4) = *(const float4*)&As[kk][tr * 8 + 4];
            *(float4*)(br)     = *(const float4*)&Bs[kk][tc * 8];
            *(float4*)(br + 4) = *(const float4*)&Bs[kk][tc * 8 + 4];
            #pragma unroll
            for (int i = 0; i < 8; ++i)
                #pragma unroll
                for (int j = 0; j < 8; ++j)
                    acc[i][j] = fmaf(ar[i], br[j], acc[i][j]);
        }
    }
    #pragma unroll
    for (int i = 0; i < 8; ++i) {
        int m = m0 + tr * 8 + i;
        float g = 1.0f;
        if (EPI == 1) g = (counts[bidx[m]] > 1) ? gamma[0] : 0.0f;
        #pragma unroll
        for (int j = 0; j < 8; ++j) {
            int n = n0 + tc * 8 + j;
            float v = acc[i][j] + bias[n];
            if (EPI == 1) v *= g;
            C[(size_t)m * Nc + n] = v;
        }
    }
}

// ---------------------------------------------------------------------------
// Block-diagonal attention, tiled/2D-parallel (flash style).
// One block per (group, head, qtile-slice).  Q tile 64 rows staged in LDS;
// K/V tiles of 32 rows staged per iteration.  Chunk-column XOR swizzle
// keeps every LDS read <=2-way.  Thread (tr,tc): score phase computes a
// 4q x 2k sub-tile via float4 dots; softmax row-reduce over the 16-lane tc
// group; PV phase redistributes P via in-wave __shfl (no P buffer, no extra
// barriers).  m/l/acc state is per-thread for its 4 q-rows (same rows in
// both phases).  All __syncthreads() in uniform control flow.
// ---------------------------------------------------------------------------
#define FMA4(d, a, b) { d.x = fmaf(a.x, b.x, d.x); d.y = fmaf(a.y, b.y, d.y); \
                        d.z = fmaf(a.z, b.z, d.z); d.w = fmaf(a.w, b.w, d.w); }

__global__ __launch_bounds__(256) void attn_kernel(
    const float* __restrict__ qkv, const int* __restrict__ sorted,
    const int* __restrict__ offsets, const int* __restrict__ counts,
    float* __restrict__ attn_out)
{
    const int g = blockIdx.x, h = blockIdx.y;
    const int cnt = counts[g], off = offsets[g];
    if (cnt == 0) return;

    __shared__ float qs[64 * 128];   // [row][chunk^swz]  32 KB
    __shared__ float kt[32 * 128];   // 16 KB
    __shared__ float vt[32 * 128];   // 16 KB
    float4* qs4 = (float4*)qs;
    float4* kt4 = (float4*)kt;
    float4* vt4 = (float4*)vt;

    const int tid = threadIdx.x;
    const int tr  = tid >> 4;        // 0..15: q-row group (rows 4tr..4tr+3)
    const int tc  = tid & 15;        // score: k cols 2tc,2tc+1; PV: d cols 8tc..8tc+7
    const int trl = tr & 3;          // wave-local row group
    const float scale = 0.08838834764831845f;   // 1/sqrt(128)
    const int nTiles = (cnt + 31) / 32;

    for (int qt = blockIdx.z; qt * 64 < cnt; qt += gridDim.z) {
        const int qbase = qt * 64;
        const int qrem  = cnt - qbase;           // > 0
        __syncthreads();                         // prior qt's reads done
        // ---- stage Q tile (<=64 rows x 128), swizzled chunk columns ----
        #pragma unroll
        for (int it = 0; it < 8; ++it) {
            int fi = tid + it * 256;             // 0..2047
            int r = fi >> 5, c = fi & 31;
            if (r < qrem) {
                int row = sorted[off + qbase + r];
                qs4[r * 32 + (c ^ ((r >> 1) & 7))] =
                    *(const float4*)(qkv + (size_t)row * QKV_DIM + h * HD + c * 4);
            }
        }

        float m_run[4], l_run[4], acc[4][8];
        #pragma unroll
        for (int i = 0; i < 4; ++i) {
            m_run[i] = -3.0e38f; l_run[i] = 0.f;
            #pragma unroll
            for (int d = 0; d < 8; ++d) acc[i][d] = 0.f;
        }

        for (int t = 0; t < nTiles; ++t) {
            const int tbase = t * 32;
            const int trows = min(32, cnt - tbase);
            __syncthreads();                     // qs staged / prior kt,vt reads done
            // ---- stage K,V tile (<=32 rows x 128), swizzled; zero V tail ----
            #pragma unroll
            for (int it = 0; it < 4; ++it) {
                int fi = tid + it * 256;         // 0..1023
                int r = fi >> 5, c = fi & 31;
                int sw = r * 32 + (c ^ ((r >> 1) & 7));
                if (r < trows) {
                    int row = sorted[off + tbase + r];
                    const float* base = qkv + (size_t)row * QKV_DIM + h * HD;
                    kt4[sw] = *(const float4*)(base + C_DIM + c * 4);
                    vt4[sw] = *(const float4*)(base + 2 * C_DIM + c * 4);
                } else {
                    float4 z; z.x = z.y = z.z = z.w = 0.f;
                    vt4[sw] = z;                 // guard 0*uninit in PV tail
                }
            }
            __syncthreads();

            // ---- QK^T microkernel: 4q x 2k per thread over d=128 ----
            float4 sa[4][2];
            #pragma unroll
            for (int i = 0; i < 4; ++i) {
                sa[i][0].x = sa[i][0].y = sa[i][0].z = sa[i][0].w = 0.f;
                sa[i][1].x = sa[i][1].y = sa[i][1].z = sa[i][1].w = 0.f;
            }
            const int sq0 = (2 * tr) & 7, sq1 = (2 * tr + 1) & 7, skc = tc & 7;
            #pragma unroll 8
            for (int d4 = 0; d4 < 32; ++d4) {
                float4 a0 = qs4[(4 * tr + 0) * 32 + (d4 ^ sq0)];
                float4 a1 = qs4[(4 * tr + 1) * 32 + (d4 ^ sq0)];
                float4 a2 = qs4[(4 * tr + 2) * 32 + (d4 ^ sq1)];
                float4 a3 = qs4[(4 * tr + 3) * 32 + (d4 ^ sq1)];
                float4 b0 = kt4[(2 * tc + 0) * 32 + (d4 ^ skc)];
                float4 b1 = kt4[(2 * tc + 1) * 32 + (d4 ^ skc)];
                FMA4(sa[0][0], a0, b0); FMA4(sa[0][1], a0, b1);
                FMA4(sa[1][0], a1, b0); FMA4(sa[1][1], a1, b1);
                FMA4(sa[2][0], a2, b0); FMA4(sa[2][1], a2, b1);
                FMA4(sa[3][0], a3, b0); FMA4(sa[3][1], a3, b1);
            }

            // ---- online softmax (row state per thread, 16-lane reduces) ----
            float p[4][2], alpha[4];
            #pragma unroll
            for (int i = 0; i < 4; ++i) {
                float s0 = (sa[i][0].x + sa[i][0].y) + (sa[i][0].z + sa[i][0].w);
                float s1 = (sa[i][1].x + sa[i][1].y) + (sa[i][1].z + sa[i][1].w);
                s0 = (tbase + 2 * tc     < cnt) ? s0 * scale : -3.0e38f;
                s1 = (tbase + 2 * tc + 1 < cnt) ? s1 * scale : -3.0e38f;
                float tm = fmaxf(s0, s1);
                #pragma unroll
                for (int m = 1; m < 16; m <<= 1) tm = fmaxf(tm, __shfl_xor(tm, m));
                float mn = fmaxf(m_run[i], tm);
                float al = __expf(m_run[i] - mn);
                float p0 = __expf(s0 - mn);
                float p1 = __expf(s1 - mn);
                float rs = p0 + p1;
                #pragma unroll
                for (int m = 1; m < 16; m <<= 1) rs += __shfl_xor(rs, m);
                l_run[i] = l_run[i] * al + rs;
                m_run[i] = mn;
                alpha[i] = al;
                p[i][0] = p0; p[i][1] = p1;
            }
            #pragma unroll
            for (int i = 0; i < 4; ++i)
                #pragma unroll
                for (int d = 0; d < 8; ++d) acc[i][d] *= alpha[i];

            // ---- PV microkernel: P redistributed via in-wave shuffles ----
            #pragma unroll 8
            for (int kk = 0; kk < 32; ++kk) {
                int src = trl * 16 + (kk >> 1);
                float4 v0 = vt4[kk * 32 + ((2 * tc + 0) ^ ((kk >> 1) & 7))];
                float4 v1 = vt4[kk * 32 + ((2 * tc + 1) ^ ((kk >> 1) & 7))];
                #pragma unroll
                for (int i = 0; i < 4; ++i) {
                    float pk = __shfl((kk & 1) ? p[i][1] : p[i][0], src);
                    acc[i][0] = fmaf(pk, v0.x, acc[i][0]);
                    acc[i][1] = fmaf(pk, v0.y, acc[i][1]);
                    acc[i][2] = fmaf(pk, v0.z, acc[i][2]);
                    acc[i][3] = fmaf(pk, v0.w, acc[i][3]);
                    acc[i][4] = fmaf(pk, v1.x, acc[i][4]);
                    acc[i][5] = fmaf(pk, v1.y, acc[i][5]);
                    acc[i][6] = fmaf(pk, v1.z, acc[i][6]);
                    acc[i][7] = fmaf(pk, v1.w, acc[i][7]);
                }
            }
        }

        // ---- store O = acc / l for valid rows ----
        #pragma unroll
        for (int i = 0; i < 4; ++i) {
            int ql = 4 * tr + i;
            if (qbase + ql < cnt) {
                int row = sorted[off + qbase + ql];
                float inv = 1.0f / l_run[i];
                float* op = attn_out + (size_t)row * C_DIM + h * HD + tc * 8;
                float4 o0, o1;
                o0.x = acc[i][0] * inv; o0.y = acc[i][1] * inv;
                o0.z = acc[i][2] * inv; o0.w = acc[i][3] * inv;
                o1.x = acc[i][4] * inv; o1.y = acc[i][5] * inv;
                o1.z = acc[i][6] * inv; o1.w = acc[i][7] * inv;
                *(float4*)op       = o0;
                *(float4*)(op + 4) = o1;
            }
        }
    }
}

// ---------------------------------------------------------------------------
// y[n][c][hw] = x[n][c][hw] + delta[n][c]
// ---------------------------------------------------------------------------
__global__ __launch_bounds__(256) void final_add(
    const float* __restrict__ x, const float* __restrict__ delta,
    float* __restrict__ out)
{
    size_t i = (size_t)blockIdx.x * 256 + threadIdx.x;
    float4 xv = ((const float4*)x)[i];
    float  d  = delta[i >> 4];
    float4 o;
    o.x = xv.x + d; o.y = xv.y + d; o.z = xv.z + d; o.w = xv.w + d;
    ((float4*)out)[i] = o;
}

// ---------------------------------------------------------------------------
extern "C" void kernel_launch(void* const* d_in, const int* in_sizes, int n_in,
                              void* d_out, int out_size, void* d_ws, size_t ws_size,
                              hipStream_t stream)
{
    const float* x          = (const float*)d_in[0];
    const int*   bidx       = (const int*)d_in[1];
    const float* ln_w       = (const float*)d_in[2];
    const float* ln_b       = (const float*)d_in[3];
    const float* in_proj_w  = (const float*)d_in[4];
    const float* in_proj_b  = (const float*)d_in[5];
    const float* out_proj_w = (const float*)d_in[6];
    const float* out_proj_b = (const float*)d_in[7];
    const float* gamma      = (const float*)d_in[8];
    float* out = (float*)d_out;

    float* ws       = (float*)d_ws;
    float* feat     = ws;                                  // 2M floats
    float* qkv      = ws + (size_t)2  * 1024 * 1024;       // 6M floats
    float* attn_out = ws + (size_t)8  * 1024 * 1024;       // 2M floats
    float* delta    = ws + (size_t)10 * 1024 * 1024;       // 2M floats
    int*   ints     = (int*)(ws + (size_t)12 * 1024 * 1024);
    int*   counts   = ints;                                // 32
    int*   offsets  = ints + 32;                           // 32
    int*   sorted   = ints + 64;                           // 2048

    group_setup<<<dim3(1), dim3(256), 0, stream>>>(bidx, counts, offsets, sorted);
    feat_mean<<<dim3(131072), dim3(256), 0, stream>>>(x, feat);
    layernorm<<<dim3(2048), dim3(256), 0, stream>>>(feat, ln_w, ln_b);
    gemm_bt<0><<<dim3(24, 16), dim3(256), 0, stream>>>(
        feat, in_proj_w, in_proj_b, qkv, 2048, 3072, 1024, nullptr, nullptr, nullptr);
    attn_kernel<<<dim3(32, 8, 2), dim3(256), 0, stream>>>(qkv, sorted, offsets, counts, attn_out);
    gemm_bt<1><<<dim3(8, 16), dim3(256), 0, stream>>>(
        attn_out, out_proj_w, out_proj_b, delta, 2048, 1024, 1024, gamma, counts, bidx);
    final_add<<<dim3(131072), dim3(256), 0, stream>>>(x, delta, out);
}